// Round 4
// baseline (516.909 us; speedup 1.0000x reference)
//
#include <hip/hip_runtime.h>
#include <math.h>

// Mask R-CNN cascade head.
// - ONE prep_all dispatch: all 3 stages' weight transposes (fp32->bf16, (K,N)->(N,K))
//   + roi/valid init + pre_b/pre_s zero.
// - ONE feat_all dispatch: all 4 FPN levels [C][H][W] fp32 -> [H][W][C] bf16.
// - Per stage: pool -> FC1 MFMA (split-K 14) -> reduce+bias+relu -> FC2 MFMA
//   (z=1, fused bias+relu epilogue) -> heads MFMA (z=4) -> decode.
// - 21 dispatches total.

#define NROI 256
#define NCLS 80
#define APITCH 40  // 32 k + 8 pad (bf16 elems); 80B row pitch keeps 16B alignment

typedef __attribute__((ext_vector_type(8))) short short8;
typedef __attribute__((ext_vector_type(4))) float f32x4;

struct __attribute__((aligned(8))) US4 { unsigned short a, b, c, d; };

__device__ __forceinline__ unsigned short f2bf(float f) {
  unsigned u = __builtin_bit_cast(unsigned, f);
  unsigned r = (u + 0x7FFFu + ((u >> 16) & 1u)) >> 16;  // RNE
  return (unsigned short)r;
}
__device__ __forceinline__ float bf2f(unsigned short u) {
  return __builtin_bit_cast(float, (unsigned)u << 16);
}

// ---------------- prep_all: weight transposes + init + zero, one dispatch ------
struct PrepArgs {
  const float* W1[3];
  const float* W2[3];
  const float* Wc[3];
  const float* Wl[3];
  unsigned short* Wt1[3];
  unsigned short* Wt2[3];
  unsigned short* Wth[3];
  const float* rois;
  float* roi;
  float* valid;
  float* zero_base;
  int zero_count;
};

// block counts: W1 3*12544=37632 | W2 3*1024 -> 40704 | heads 3*512 -> 42240
// | init 1 -> 42241 | zero 100 -> 42341
__global__ __launch_bounds__(256) void prep_all(PrepArgs a) {
  __shared__ unsigned short tile[32][33];
  const int b = blockIdx.x;
  const int t = threadIdx.x;
  const int r = t >> 3;
  const int c4 = (t & 7) * 4;

  if (b < 37632) {  // W1 transpose with K-permutation: kd = p*256 + c
    int s = b / 12544;
    int tau = b % 12544;
    int kd0 = (tau % 392) * 32;
    int n0 = (tau / 392) * 32;
    int p = kd0 >> 8;
    int c0 = kd0 & 255;
    int k_src = (c0 + r) * 49 + p;
    float4 v = *(const float4*)(a.W1[s] + (size_t)k_src * 1024 + n0 + c4);
    tile[r][c4 + 0] = f2bf(v.x);
    tile[r][c4 + 1] = f2bf(v.y);
    tile[r][c4 + 2] = f2bf(v.z);
    tile[r][c4 + 3] = f2bf(v.w);
    __syncthreads();
    US4 o = {tile[c4 + 0][r], tile[c4 + 1][r], tile[c4 + 2][r], tile[c4 + 3][r]};
    *(US4*)(a.Wt1[s] + (size_t)(n0 + r) * 12544 + kd0 + c4) = o;
  } else if (b < 40704) {  // W2 (1024,1024) -> (1024,1024)^T
    int bb = b - 37632;
    int s = bb / 1024;
    int tau = bb % 1024;
    int k0 = (tau % 32) * 32;
    int n0 = (tau / 32) * 32;
    float4 v = *(const float4*)(a.W2[s] + (size_t)(k0 + r) * 1024 + n0 + c4);
    tile[r][c4 + 0] = f2bf(v.x);
    tile[r][c4 + 1] = f2bf(v.y);
    tile[r][c4 + 2] = f2bf(v.z);
    tile[r][c4 + 3] = f2bf(v.w);
    __syncthreads();
    US4 o = {tile[c4 + 0][r], tile[c4 + 1][r], tile[c4 + 2][r], tile[c4 + 3][r]};
    *(US4*)(a.Wt2[s] + (size_t)(n0 + r) * 1024 + k0 + c4) = o;
  } else if (b < 42240) {  // fused heads [Wc | Wl | pad] -> (512, 1024)
    int bb = b - 40704;
    int s = bb / 512;
    int tau = bb % 512;
    int k0 = (tau % 32) * 32;
    int n0 = (tau / 32) * 32;  // < 512
#pragma unroll
    for (int j = 0; j < 4; j++) {
      int nn = n0 + c4 + j;
      float v = 0.0f;
      if (nn < 81) v = a.Wc[s][(size_t)(k0 + r) * 81 + nn];
      else if (nn < 405) v = a.Wl[s][(size_t)(k0 + r) * 324 + (nn - 81)];
      tile[r][c4 + j] = f2bf(v);
    }
    __syncthreads();
    US4 o = {tile[c4 + 0][r], tile[c4 + 1][r], tile[c4 + 2][r], tile[c4 + 3][r]};
    *(US4*)(a.Wth[s] + (size_t)(n0 + r) * 1024 + k0 + c4) = o;
  } else if (b == 42240) {  // init roi + valid
    for (int i = t; i < NROI * 4; i += 256) a.roi[i] = a.rois[i];
    a.valid[t] = 1.0f;  // t < 256 == NROI
  } else {  // zero pre_b/pre_s
    int base = (b - 42241) * 1024 + t;
#pragma unroll
    for (int j = 0; j < 4; j++) {
      int ii = base + j * 256;
      if (ii < a.zero_count) a.zero_base[ii] = 0.0f;
    }
  }
}

// ---------------- feat_all: all 4 FPN levels (C=256, HW) -> (HW, 256) bf16 ------
// blocks: P0 16384 | P1 -> 20480 | P2 -> 21504 | P3 -> 21760
__global__ __launch_bounds__(256) void feat_all(
    const float* __restrict__ P0, const float* __restrict__ P1,
    const float* __restrict__ P2, const float* __restrict__ P3,
    unsigned short* __restrict__ Pb0, unsigned short* __restrict__ Pb1,
    unsigned short* __restrict__ Pb2, unsigned short* __restrict__ Pb3) {
  __shared__ unsigned short tile[32][33];
  const int b = blockIdx.x;
  const int t = threadIdx.x;
  const float* src;
  unsigned short* dst;
  int N, tau;
  if (b < 16384)      { src = P0; dst = Pb0; N = 65536; tau = b; }
  else if (b < 20480) { src = P1; dst = Pb1; N = 16384; tau = b - 16384; }
  else if (b < 21504) { src = P2; dst = Pb2; N = 4096;  tau = b - 20480; }
  else                { src = P3; dst = Pb3; N = 1024;  tau = b - 21504; }
  int k0 = (tau & 7) * 32;
  int n0 = (tau >> 3) * 32;
  int r = t >> 3;
  int c4 = (t & 7) * 4;
  float4 v = *(const float4*)(src + (size_t)(k0 + r) * N + n0 + c4);
  tile[r][c4 + 0] = f2bf(v.x);
  tile[r][c4 + 1] = f2bf(v.y);
  tile[r][c4 + 2] = f2bf(v.z);
  tile[r][c4 + 3] = f2bf(v.w);
  __syncthreads();
  US4 o = {tile[c4 + 0][r], tile[c4 + 1][r], tile[c4 + 2][r], tile[c4 + 3][r]};
  *(US4*)(dst + (size_t)(n0 + r) * 256 + k0 + c4) = o;
}

// ---------------- ROI align pool: [H][W][C] bf16 features ----------------
__global__ __launch_bounds__(256) void pool_kernel2(
    const unsigned short* __restrict__ Pb0, const unsigned short* __restrict__ Pb1,
    const unsigned short* __restrict__ Pb2, const unsigned short* __restrict__ Pb3,
    const float* __restrict__ roi, unsigned short* __restrict__ pooled) {
  int t = threadIdx.x;
  int n = blockIdx.y;
  int p = blockIdx.x * 4 + (t >> 6);
  if (p >= 49) return;
  int lane = t & 63;
  int c4 = lane * 4;
  int py = p / 7, px = p % 7;

  float r0 = roi[n * 4 + 0];
  float r1 = roi[n * 4 + 1];
  float r2 = roi[n * 4 + 2];
  float r3 = roi[n * 4 + 3];

  float area = (r2 - r0 + 1.0f) * (r3 - r1 + 1.0f);
  float lf = floorf(4.0f + log2f(sqrtf(area) / 224.0f));
  lf = fminf(fmaxf(lf, 2.0f), 5.0f);
  int lvl = (int)lf - 2;

  float scale;
  int H;
  const unsigned short* fb;
  if (lvl == 0)      { scale = 0.25f;    H = 256; fb = Pb0; }
  else if (lvl == 1) { scale = 0.125f;   H = 128; fb = Pb1; }
  else if (lvl == 2) { scale = 0.0625f;  H = 64;  fb = Pb2; }
  else               { scale = 0.03125f; H = 32;  fb = Pb3; }
  int W = H;

  float y1 = r0 * scale;
  float x1 = r1 * scale;
  float rh = fmaxf(r2 * scale - y1, 1.0f);
  float rw = fmaxf(r3 * scale - x1, 1.0f);
  float bh = rh * (1.0f / 7.0f);
  float bw = rw * (1.0f / 7.0f);

  float a0 = 0.f, a1 = 0.f, a2 = 0.f, a3 = 0.f;
#pragma unroll
  for (int ry = 0; ry < 2; ry++) {
    float yy = y1 + ((float)py + ((float)ry + 0.5f) * 0.5f) * bh;
    bool vy = (yy > -1.0f) && (yy < (float)H);
    float ycl = fminf(fmaxf(yy, 0.0f), (float)(H - 1));
    float y0f = floorf(ycl);
    float ly = ycl - y0f;
    int y0i = (int)y0f;
    int y1i = min(y0i + 1, H - 1);
#pragma unroll
    for (int rx = 0; rx < 2; rx++) {
      float xx = x1 + ((float)px + ((float)rx + 0.5f) * 0.5f) * bw;
      bool vx = (xx > -1.0f) && (xx < (float)W);
      float xcl = fminf(fmaxf(xx, 0.0f), (float)(W - 1));
      float x0f = floorf(xcl);
      float lx = xcl - x0f;
      int x0i = (int)x0f;
      int x1i = min(x0i + 1, W - 1);
      float w00 = (1.f - ly) * (1.f - lx);
      float w01 = (1.f - ly) * lx;
      float w10 = ly * (1.f - lx);
      float w11 = ly * lx;
      if (!(vy && vx)) { w00 = w01 = w10 = w11 = 0.f; }
      ushort4 f00 = *(const ushort4*)(fb + ((size_t)(y0i * W + x0i) * 256 + c4));
      ushort4 f01 = *(const ushort4*)(fb + ((size_t)(y0i * W + x1i) * 256 + c4));
      ushort4 f10 = *(const ushort4*)(fb + ((size_t)(y1i * W + x0i) * 256 + c4));
      ushort4 f11 = *(const ushort4*)(fb + ((size_t)(y1i * W + x1i) * 256 + c4));
      a0 += bf2f(f00.x) * w00 + bf2f(f01.x) * w01 + bf2f(f10.x) * w10 + bf2f(f11.x) * w11;
      a1 += bf2f(f00.y) * w00 + bf2f(f01.y) * w01 + bf2f(f10.y) * w10 + bf2f(f11.y) * w11;
      a2 += bf2f(f00.z) * w00 + bf2f(f01.z) * w01 + bf2f(f10.z) * w10 + bf2f(f11.z) * w11;
      a3 += bf2f(f00.w) * w00 + bf2f(f01.w) * w01 + bf2f(f10.w) * w10 + bf2f(f11.w) * w11;
    }
  }
  ushort4 o;
  o.x = f2bf(a0 * 0.25f);
  o.y = f2bf(a1 * 0.25f);
  o.z = f2bf(a2 * 0.25f);
  o.w = f2bf(a3 * 0.25f);
  *(ushort4*)(pooled + (size_t)n * 12544 + p * 256 + c4) = o;
}

// ---------------- bf16 MFMA GEMM: C = A(MxK) @ Bt(NxK)^T ----------------
// If fused_out != null (z must be 1): epilogue = bias + relu -> bf16 fused_out.
// Else: write fp32 partial Cpart[z].
__global__ __launch_bounds__(256) void gemm_bf16(
    const unsigned short* __restrict__ A, const unsigned short* __restrict__ B,
    float* __restrict__ Cpart, int M, int N, int K, int iters,
    const float* __restrict__ bias, unsigned short* __restrict__ fused_out) {
  __shared__ unsigned short As[128 * APITCH];
  __shared__ unsigned short Bs[128 * APITCH];
  const int t = threadIdx.x;
  const int n0 = blockIdx.x * 128;
  const int m0 = blockIdx.y * 128;
  const size_t kt0 = (size_t)blockIdx.z * iters * 32;

  const int row = t >> 2;
  const int off = (t & 3) * 8;
  const unsigned short* pa0 = A + (size_t)(m0 + row) * K + kt0 + off;
  const unsigned short* pa1 = pa0 + (size_t)64 * K;
  const unsigned short* pb0 = B + (size_t)(n0 + row) * K + kt0 + off;
  const unsigned short* pb1 = pb0 + (size_t)64 * K;

  const int lane = t & 63;
  const int wave = t >> 6;
  const int wm = (wave >> 1) * 64;
  const int wn = (wave & 1) * 64;
  const int fr = lane & 15;
  const int kq = (lane >> 4) * 8;

  f32x4 acc[4][4];
#pragma unroll
  for (int i = 0; i < 4; i++)
#pragma unroll
    for (int j = 0; j < 4; j++) acc[i][j] = (f32x4){0.f, 0.f, 0.f, 0.f};

  uint4 ra0 = *(const uint4*)pa0;
  uint4 ra1 = *(const uint4*)pa1;
  uint4 rb0 = *(const uint4*)pb0;
  uint4 rb1 = *(const uint4*)pb1;

  for (int it = 0; it < iters; ++it) {
    *(uint4*)&As[row * APITCH + off] = ra0;
    *(uint4*)&As[(row + 64) * APITCH + off] = ra1;
    *(uint4*)&Bs[row * APITCH + off] = rb0;
    *(uint4*)&Bs[(row + 64) * APITCH + off] = rb1;
    __syncthreads();
    if (it + 1 < iters) {
      int d = (it + 1) * 32;
      ra0 = *(const uint4*)(pa0 + d);
      ra1 = *(const uint4*)(pa1 + d);
      rb0 = *(const uint4*)(pb0 + d);
      rb1 = *(const uint4*)(pb1 + d);
    }
    short8 af[4], bfv[4];
#pragma unroll
    for (int f = 0; f < 4; f++)
      af[f] = *(const short8*)&As[(wm + f * 16 + fr) * APITCH + kq];
#pragma unroll
    for (int f = 0; f < 4; f++)
      bfv[f] = *(const short8*)&Bs[(wn + f * 16 + fr) * APITCH + kq];
#pragma unroll
    for (int fm = 0; fm < 4; fm++)
#pragma unroll
      for (int fn = 0; fn < 4; fn++)
        acc[fm][fn] = __builtin_amdgcn_mfma_f32_16x16x32_bf16(af[fm], bfv[fn],
                                                              acc[fm][fn], 0, 0, 0);
    __syncthreads();
  }

  const int colb = n0 + wn + fr;
  const int rowb = m0 + wm + (lane >> 4) * 4;
  if (fused_out) {
#pragma unroll
    for (int fm = 0; fm < 4; fm++)
#pragma unroll
      for (int fn = 0; fn < 4; fn++) {
        int col = colb + fn * 16;
        float bv = bias[col];
#pragma unroll
        for (int r = 0; r < 4; r++) {
          float v = fmaxf(acc[fm][fn][r] + bv, 0.0f);
          fused_out[(size_t)(rowb + fm * 16 + r) * N + col] = f2bf(v);
        }
      }
  } else {
    float* Cp = Cpart + (size_t)blockIdx.z * M * N;
#pragma unroll
    for (int fm = 0; fm < 4; fm++)
#pragma unroll
      for (int fn = 0; fn < 4; fn++)
#pragma unroll
        for (int r = 0; r < 4; r++)
          Cp[(size_t)(rowb + fm * 16 + r) * N + (colb + fn * 16)] = acc[fm][fn][r];
  }
}

// ---------------- split-K reduce + bias + relu -> bf16 (FC1) ----------------
__global__ __launch_bounds__(256) void reduce_bias_relu(
    const float* __restrict__ parts, int nparts, const float* __restrict__ bias,
    unsigned short* __restrict__ outb) {
  int i = blockIdx.x * 256 + threadIdx.x;  // total 256*1024
  float s = 0.0f;
  for (int p = 0; p < nparts; ++p) s += parts[(size_t)p * 262144 + i];
  s = fmaxf(s + bias[i & 1023], 0.0f);
  outb[i] = f2bf(s);
}

// ---------------- decode ----------------
__global__ __launch_bounds__(128) void decode_kernel(
    const float* __restrict__ headp, const float* __restrict__ bc,
    const float* __restrict__ bl,
    float* __restrict__ roi, float* __restrict__ valid,
    float* __restrict__ pre_b, float* __restrict__ pre_s,
    float st0, float st1, float st2, float st3, int stage) {
  int n = blockIdx.x;
  int t = threadIdx.x;
  __shared__ float red[128];
  __shared__ int redi[128];
  __shared__ float sroi[4];
  __shared__ float boxes[NCLS][4];

  if (t < 4) sroi[t] = roi[n * 4 + t];
  float l = -INFINITY;
  if (t < 81) {
    float s = 0.f;
#pragma unroll
    for (int z = 0; z < 4; z++) s += headp[(size_t)z * 131072 + n * 512 + t];
    l = s + bc[t];
  }
  red[t] = l;
  __syncthreads();
#pragma unroll
  for (int s = 64; s > 0; s >>= 1) {
    if (t < s) red[t] = fmaxf(red[t], red[t + s]);
    __syncthreads();
  }
  float mx = red[0];
  __syncthreads();
  red[t] = (t < 81) ? expf(l - mx) : 0.0f;
  __syncthreads();
#pragma unroll
  for (int s = 64; s > 0; s >>= 1) {
    if (t < s) red[t] += red[t + s];
    __syncthreads();
  }
  float denom = red[0];
  __syncthreads();

  float score = -INFINITY;
  if (t < NCLS) {
    float lj = 0.f;
#pragma unroll
    for (int z = 0; z < 4; z++) lj += headp[(size_t)z * 131072 + n * 512 + (t + 1)];
    lj += bc[t + 1];
    score = expf(lj - mx) / denom;
    float lp[4];
#pragma unroll
    for (int j = 0; j < 4; j++) {
      float s = 0.f;
#pragma unroll
      for (int z = 0; z < 4; z++)
        s += headp[(size_t)z * 131072 + n * 512 + 81 + (t + 1) * 4 + j];
      lp[j] = s + bl[(t + 1) * 4 + j];
    }
    float dy = lp[0] * st0;
    float dx = lp[1] * st1;
    float dh = lp[2] * st2;
    float dw = lp[3] * st3;
    float h_ = sroi[2] - sroi[0];
    float w_ = sroi[3] - sroi[1];
    float cy = sroi[0] + h_ * 0.5f;
    float cx = sroi[1] + w_ * 0.5f;
    float ny = dy * h_ + cy;
    float nx = dx * w_ + cx;
    float nh = expf(dh) * h_;
    float nw = expf(dw) * w_;
    float b0 = ny - nh * 0.5f;
    float b1v = nx - nw * 0.5f;
    float b2v = ny + nh * 0.5f;
    float b3v = nx + nw * 0.5f;
    int o = (n * NCLS + t) * 4;
    pre_b[o + 0] += b0;
    pre_b[o + 1] += b1v;
    pre_b[o + 2] += b2v;
    pre_b[o + 3] += b3v;
    pre_s[n * NCLS + t] += score;
    boxes[t][0] = b0;
    boxes[t][1] = b1v;
    boxes[t][2] = b2v;
    boxes[t][3] = b3v;
  }
  red[t] = score;
  redi[t] = t;
  __syncthreads();
  for (int s = 64; s > 0; s >>= 1) {
    if (t < s) {
      float o2 = red[t + s];
      int oi = redi[t + s];
      if (o2 > red[t] || (o2 == red[t] && oi < redi[t])) {
        red[t] = o2;
        redi[t] = oi;
      }
    }
    __syncthreads();
  }
  if (t == 0) {
    int best = redi[0];
    float ry1 = fminf(fmaxf(boxes[best][0], 0.0f), 1024.0f);
    float rx1 = fminf(fmaxf(boxes[best][1], 0.0f), 1024.0f);
    float ry2 = fminf(fmaxf(boxes[best][2], 0.0f), 1024.0f);
    float rx2 = fminf(fmaxf(boxes[best][3], 0.0f), 1024.0f);
    roi[n * 4 + 0] = ry1;
    roi[n * 4 + 1] = rx1;
    roi[n * 4 + 2] = ry2;
    roi[n * 4 + 3] = rx2;
    if (stage < 2) {
      float hh = ry2 - ry1, ww = rx2 - rx1;
      if (!(hh >= 16.0f && ww >= 16.0f)) valid[n] = 0.0f;
    }
  }
}

// ---------------- finalize ----------------
__global__ __launch_bounds__(256) void finalize_kernel(
    const float* __restrict__ pre_b, const float* __restrict__ pre_s,
    const float* __restrict__ valid, float* __restrict__ out) {
  int i = blockIdx.x * 256 + threadIdx.x;
  if (i < NROI * NCLS * 4) {
    int n = i / (NCLS * 4);
    out[i] = pre_b[i] * valid[n] * (1.0f / 3.0f);
  } else if (i < NROI * NCLS * 4 + NROI * NCLS) {
    int j = i - NROI * NCLS * 4;
    int n = j / NCLS;
    out[i] = pre_s[j] * valid[n] * (1.0f / 3.0f);
  }
}

extern "C" void kernel_launch(void* const* d_in, const int* in_sizes, int n_in,
                              void* d_out, int out_size, void* d_ws, size_t ws_size,
                              hipStream_t stream) {
  const float* P0 = (const float*)d_in[0];
  const float* P1 = (const float*)d_in[1];
  const float* P2 = (const float*)d_in[2];
  const float* P3 = (const float*)d_in[3];
  const float* rois = (const float*)d_in[4];
  float* out = (float*)d_out;
  float* ws = (float*)d_ws;

  // ---- ws layout (fp32 region, then bf16 region) ----
  float* roi   = ws;                      // 1024
  float* valid = roi + 1024;              // 256
  float* pre_b = valid + 256;             // 81920
  float* pre_s = pre_b + 81920;           // 20480
  float* part1 = pre_s + 20480;           // 14 * 262144
  float* parth = part1 + 14 * 262144;     // 4 * 131072
  unsigned short* pooledb = (unsigned short*)(parth + 4 * 131072);  // 256*12544
  unsigned short* Wt1s = pooledb + (size_t)256 * 12544;   // 3 * 1024*12544
  unsigned short* Wt2s = Wt1s + (size_t)3 * 1024 * 12544; // 3 * 1024*1024
  unsigned short* Wths = Wt2s + (size_t)3 * 1024 * 1024;  // 3 * 512*1024
  unsigned short* h1b = Wths + (size_t)3 * 512 * 1024;    // 256*1024
  unsigned short* h2b = h1b + (size_t)256 * 1024;         // 256*1024
  unsigned short* Pb0 = h2b + (size_t)256 * 1024;         // 65536*256
  unsigned short* Pb1 = Pb0 + (size_t)65536 * 256;        // 16384*256
  unsigned short* Pb2 = Pb1 + (size_t)16384 * 256;        // 4096*256
  unsigned short* Pb3 = Pb2 + (size_t)4096 * 256;         // 1024*256
  // total ~= 160 MB (< 256 MiB ws)

  PrepArgs pa;
  for (int s = 0; s < 3; s++) {
    pa.W1[s] = (const float*)d_in[5 + s * 8 + 0];
    pa.W2[s] = (const float*)d_in[5 + s * 8 + 2];
    pa.Wc[s] = (const float*)d_in[5 + s * 8 + 4];
    pa.Wl[s] = (const float*)d_in[5 + s * 8 + 6];
    pa.Wt1[s] = Wt1s + (size_t)s * 1024 * 12544;
    pa.Wt2[s] = Wt2s + (size_t)s * 1024 * 1024;
    pa.Wth[s] = Wths + (size_t)s * 512 * 1024;
  }
  pa.rois = rois;
  pa.roi = roi;
  pa.valid = valid;
  pa.zero_base = pre_b;
  pa.zero_count = 81920 + 20480;

  feat_all<<<21760, 256, 0, stream>>>(P0, P1, P2, P3, Pb0, Pb1, Pb2, Pb3);
  prep_all<<<42341, 256, 0, stream>>>(pa);

  const float stds[3][4] = {
      {0.1f, 0.1f, 0.2f, 0.2f},
      {0.05f, 0.05f, 0.1f, 0.1f},
      {1.0f / 30.0f, 1.0f / 30.0f, 1.0f / 15.0f, 1.0f / 15.0f}};

  for (int s = 0; s < 3; s++) {
    const float* b1 = (const float*)d_in[5 + s * 8 + 1];
    const float* b2 = (const float*)d_in[5 + s * 8 + 3];
    const float* bc = (const float*)d_in[5 + s * 8 + 5];
    const float* bl = (const float*)d_in[5 + s * 8 + 7];

    pool_kernel2<<<dim3(13, 256), 256, 0, stream>>>(Pb0, Pb1, Pb2, Pb3, roi, pooledb);

    // FC1: (256x12544)@(12544x1024)^T -> part1[14], iters = 392/14 = 28
    gemm_bf16<<<dim3(8, 2, 14), 256, 0, stream>>>(
        pooledb, pa.Wt1[s], part1, 256, 1024, 12544, 28, nullptr, nullptr);
    reduce_bias_relu<<<1024, 256, 0, stream>>>(part1, 14, b1, h1b);

    // FC2: (256x1024)@(1024x1024)^T, z=1 with fused bias+relu -> h2b bf16
    gemm_bf16<<<dim3(8, 2, 1), 256, 0, stream>>>(
        h1b, pa.Wt2[s], nullptr, 256, 1024, 1024, 32, b2, h2b);

    // fused heads: (256x1024)@(1024x512)^T -> parth[4], iters = 8
    gemm_bf16<<<dim3(4, 2, 4), 256, 0, stream>>>(
        h2b, pa.Wth[s], parth, 256, 512, 1024, 8, nullptr, nullptr);

    decode_kernel<<<256, 128, 0, stream>>>(parth, bc, bl, roi, valid, pre_b, pre_s,
                                           stds[s][0], stds[s][1], stds[s][2], stds[s][3], s);
  }

  finalize_kernel<<<400, 256, 0, stream>>>(pre_b, pre_s, valid, out);
}

// Round 5
// 515.494 us; speedup vs baseline: 1.0027x; 1.0027x over previous
//
#include <hip/hip_runtime.h>
#include <math.h>

// Mask R-CNN cascade head.
// - ONE prep_all dispatch (wide 64x256 transpose tiles): all weight transposes
//   (fp32->bf16 (K,N)->(N,K)), all 4 FPN feature transposes [C][HW]->[HW][C],
//   roi/valid init, pre_b/pre_s zero.
// - Per stage: pool -> FC1 MFMA (split-K 14) -> reduce -> FC2 MFMA (split-K 8)
//   -> reduce -> heads MFMA (split-K 4) -> decode.

#define NROI 256
#define NCLS 80
#define APITCH 40   // GEMM LDS: 32 k + 8 pad (bf16 elems)
#define TP 264      // transpose LDS row pitch (256 + 8 pad, shorts)

typedef __attribute__((ext_vector_type(8))) short short8;
typedef __attribute__((ext_vector_type(4))) float f32x4;

__device__ __forceinline__ unsigned short f2bf(float f) {
  unsigned u = __builtin_bit_cast(unsigned, f);
  unsigned r = (u + 0x7FFFu + ((u >> 16) & 1u)) >> 16;  // RNE
  return (unsigned short)r;
}
__device__ __forceinline__ float bf2f(unsigned short u) {
  return __builtin_bit_cast(float, (unsigned)u << 16);
}

// ---------------- prep_all ----------------
// Block ranges:
//   [0, 2352)        W1 transpose (K-permuted), 784/stage (196 kd-tiles x 4 n-tiles)
//   [2352, 3712)     feat: P0 1024 | P1 256 | P2 64 | P3 16
//   [3712, 3904)     W2, 64/stage (16 k-tiles x 4 n-tiles)
//   [3904, 4000)     heads, 32/stage (16 k-tiles x 2 n-tiles)
//   4000             init roi/valid
//   [4001, 4101)     zero pre_b/pre_s
struct PrepArgs {
  const float* W1[3];
  const float* W2[3];
  const float* Wc[3];
  const float* Wl[3];
  unsigned short* Wt1[3];
  unsigned short* Wt2[3];
  unsigned short* Wth[3];
  const float* P[4];
  unsigned short* Pb[4];
  const float* rois;
  float* roi;
  float* valid;
  float* zero_base;
  int zero_count;
};

__global__ __launch_bounds__(256) void prep_all(PrepArgs a) {
  __shared__ unsigned short tile[64 * TP];
  const int b = blockIdx.x;
  const int t = threadIdx.x;

  const float* src = nullptr;
  unsigned short* dst = nullptr;
  size_t srcN = 0, dstP = 0;
  int k0 = 0, n0 = 0;
  int mode = 0;  // 0=plain, 1=W1-permuted, 2=heads
  int hs = 0;    // heads stage

  if (b < 2352) {  // W1
    int s = b / 784, tau = b % 784;
    int kd0 = (tau % 196) * 64;
    n0 = (tau / 196) * 256;
    src = a.W1[s]; srcN = 1024;
    dst = a.Wt1[s]; dstP = 12544;
    k0 = kd0; mode = 1;
  } else if (b < 3712) {  // features
    int x = b - 2352;
    int l, base;
    if (x < 1024)      { l = 0; base = x; }
    else if (x < 1280) { l = 1; base = x - 1024; }
    else if (x < 1344) { l = 2; base = x - 1280; }
    else               { l = 3; base = x - 1344; }
    static const int NHW[4] = {65536, 16384, 4096, 1024};
    src = a.P[l]; srcN = NHW[l];
    dst = a.Pb[l]; dstP = 256;
    k0 = (base & 3) * 64;
    n0 = (base >> 2) * 256;
  } else if (b < 3904) {  // W2
    int x = b - 3712;
    int s = x / 64, tau = x % 64;
    src = a.W2[s]; srcN = 1024;
    dst = a.Wt2[s]; dstP = 1024;
    k0 = (tau % 16) * 64;
    n0 = (tau / 16) * 256;
  } else if (b < 4000) {  // heads
    int x = b - 3904;
    hs = x / 32;
    int tau = x % 32;
    dst = a.Wth[hs]; dstP = 1024;
    k0 = (tau % 16) * 64;
    n0 = (tau / 16) * 256;
    mode = 2;
  } else if (b == 4000) {
    for (int i = t; i < NROI * 4; i += 256) a.roi[i] = a.rois[i];
    a.valid[t] = 1.0f;
    return;
  } else {
    int base = (b - 4001) * 1024 + t;
#pragma unroll
    for (int j = 0; j < 4; j++) {
      int ii = base + j * 256;
      if (ii < a.zero_count) a.zero_base[ii] = 0.0f;
    }
    return;
  }

  // ---- read 64 rows x 256 cols into LDS (bf16) ----
  const int rp = t >> 6;          // row within pass (0..3)
  const int c4 = (t & 63) * 4;    // col offset
  if (mode == 2) {
#pragma unroll 4
    for (int pass = 0; pass < 16; pass++) {
      int r = pass * 4 + rp;
      int k = k0 + r;
      unsigned short vv[4];
#pragma unroll
      for (int j = 0; j < 4; j++) {
        int nn = n0 + c4 + j;
        float v = 0.0f;
        if (nn < 81) v = a.Wc[hs][(size_t)k * 81 + nn];
        else if (nn < 405) v = a.Wl[hs][(size_t)k * 324 + (nn - 81)];
        vv[j] = f2bf(v);
      }
      *(uint2*)&tile[r * TP + c4] =
          (uint2){(unsigned)vv[0] | ((unsigned)vv[1] << 16),
                  (unsigned)vv[2] | ((unsigned)vv[3] << 16)};
    }
  } else {
    const int p_ = k0 >> 8;          // W1 permutation (mode 1)
    const int c0_ = k0 & 255;
#pragma unroll 4
    for (int pass = 0; pass < 16; pass++) {
      int r = pass * 4 + rp;
      size_t ksrc = (mode == 1) ? ((size_t)(c0_ + r) * 49 + p_) : (size_t)(k0 + r);
      float4 v = *(const float4*)(src + ksrc * srcN + n0 + c4);
      *(uint2*)&tile[r * TP + c4] =
          (uint2){(unsigned)f2bf(v.x) | ((unsigned)f2bf(v.y) << 16),
                  (unsigned)f2bf(v.z) | ((unsigned)f2bf(v.w) << 16)};
    }
  }
  __syncthreads();

  // ---- write: thread t = dest row n0+t, 64 shorts = 128B contiguous ----
  unsigned w[32];
#pragma unroll
  for (int i = 0; i < 32; i++) {
    unsigned lo = tile[(2 * i) * TP + t];
    unsigned hi = tile[(2 * i + 1) * TP + t];
    w[i] = lo | (hi << 16);
  }
  unsigned short* dp = dst + (size_t)(n0 + t) * dstP + k0;
#pragma unroll
  for (int j = 0; j < 8; j++)
    *(uint4*)(dp + j * 8) = (uint4){w[4 * j], w[4 * j + 1], w[4 * j + 2], w[4 * j + 3]};
}

// ---------------- ROI align pool: [H][W][C] bf16 features ----------------
__global__ __launch_bounds__(256) void pool_kernel2(
    const unsigned short* __restrict__ Pb0, const unsigned short* __restrict__ Pb1,
    const unsigned short* __restrict__ Pb2, const unsigned short* __restrict__ Pb3,
    const float* __restrict__ roi, unsigned short* __restrict__ pooled) {
  int t = threadIdx.x;
  int n = blockIdx.y;
  int p = blockIdx.x * 4 + (t >> 6);
  if (p >= 49) return;
  int lane = t & 63;
  int c4 = lane * 4;
  int py = p / 7, px = p % 7;

  float r0 = roi[n * 4 + 0];
  float r1 = roi[n * 4 + 1];
  float r2 = roi[n * 4 + 2];
  float r3 = roi[n * 4 + 3];

  float area = (r2 - r0 + 1.0f) * (r3 - r1 + 1.0f);
  float lf = floorf(4.0f + log2f(sqrtf(area) / 224.0f));
  lf = fminf(fmaxf(lf, 2.0f), 5.0f);
  int lvl = (int)lf - 2;

  float scale;
  int H;
  const unsigned short* fb;
  if (lvl == 0)      { scale = 0.25f;    H = 256; fb = Pb0; }
  else if (lvl == 1) { scale = 0.125f;   H = 128; fb = Pb1; }
  else if (lvl == 2) { scale = 0.0625f;  H = 64;  fb = Pb2; }
  else               { scale = 0.03125f; H = 32;  fb = Pb3; }
  int W = H;

  float y1 = r0 * scale;
  float x1 = r1 * scale;
  float rh = fmaxf(r2 * scale - y1, 1.0f);
  float rw = fmaxf(r3 * scale - x1, 1.0f);
  float bh = rh * (1.0f / 7.0f);
  float bw = rw * (1.0f / 7.0f);

  float a0 = 0.f, a1 = 0.f, a2 = 0.f, a3 = 0.f;
#pragma unroll
  for (int ry = 0; ry < 2; ry++) {
    float yy = y1 + ((float)py + ((float)ry + 0.5f) * 0.5f) * bh;
    bool vy = (yy > -1.0f) && (yy < (float)H);
    float ycl = fminf(fmaxf(yy, 0.0f), (float)(H - 1));
    float y0f = floorf(ycl);
    float ly = ycl - y0f;
    int y0i = (int)y0f;
    int y1i = min(y0i + 1, H - 1);
#pragma unroll
    for (int rx = 0; rx < 2; rx++) {
      float xx = x1 + ((float)px + ((float)rx + 0.5f) * 0.5f) * bw;
      bool vx = (xx > -1.0f) && (xx < (float)W);
      float xcl = fminf(fmaxf(xx, 0.0f), (float)(W - 1));
      float x0f = floorf(xcl);
      float lx = xcl - x0f;
      int x0i = (int)x0f;
      int x1i = min(x0i + 1, W - 1);
      float w00 = (1.f - ly) * (1.f - lx);
      float w01 = (1.f - ly) * lx;
      float w10 = ly * (1.f - lx);
      float w11 = ly * lx;
      if (!(vy && vx)) { w00 = w01 = w10 = w11 = 0.f; }
      ushort4 f00 = *(const ushort4*)(fb + ((size_t)(y0i * W + x0i) * 256 + c4));
      ushort4 f01 = *(const ushort4*)(fb + ((size_t)(y0i * W + x1i) * 256 + c4));
      ushort4 f10 = *(const ushort4*)(fb + ((size_t)(y1i * W + x0i) * 256 + c4));
      ushort4 f11 = *(const ushort4*)(fb + ((size_t)(y1i * W + x1i) * 256 + c4));
      a0 += bf2f(f00.x) * w00 + bf2f(f01.x) * w01 + bf2f(f10.x) * w10 + bf2f(f11.x) * w11;
      a1 += bf2f(f00.y) * w00 + bf2f(f01.y) * w01 + bf2f(f10.y) * w10 + bf2f(f11.y) * w11;
      a2 += bf2f(f00.z) * w00 + bf2f(f01.z) * w01 + bf2f(f10.z) * w10 + bf2f(f11.z) * w11;
      a3 += bf2f(f00.w) * w00 + bf2f(f01.w) * w01 + bf2f(f10.w) * w10 + bf2f(f11.w) * w11;
    }
  }
  ushort4 o;
  o.x = f2bf(a0 * 0.25f);
  o.y = f2bf(a1 * 0.25f);
  o.z = f2bf(a2 * 0.25f);
  o.w = f2bf(a3 * 0.25f);
  *(ushort4*)(pooled + (size_t)n * 12544 + p * 256 + c4) = o;
}

// ---------------- bf16 MFMA GEMM: Cpart[z] = A(MxK) @ Bt(NxK)^T slice ----------
__global__ __launch_bounds__(256) void gemm_bf16(
    const unsigned short* __restrict__ A, const unsigned short* __restrict__ B,
    float* __restrict__ Cpart, int M, int N, int K, int iters) {
  __shared__ unsigned short As[128 * APITCH];
  __shared__ unsigned short Bs[128 * APITCH];
  const int t = threadIdx.x;
  const int n0 = blockIdx.x * 128;
  const int m0 = blockIdx.y * 128;
  const size_t kt0 = (size_t)blockIdx.z * iters * 32;

  const int row = t >> 2;
  const int off = (t & 3) * 8;
  const unsigned short* pa0 = A + (size_t)(m0 + row) * K + kt0 + off;
  const unsigned short* pa1 = pa0 + (size_t)64 * K;
  const unsigned short* pb0 = B + (size_t)(n0 + row) * K + kt0 + off;
  const unsigned short* pb1 = pb0 + (size_t)64 * K;

  const int lane = t & 63;
  const int wave = t >> 6;
  const int wm = (wave >> 1) * 64;
  const int wn = (wave & 1) * 64;
  const int fr = lane & 15;
  const int kq = (lane >> 4) * 8;

  f32x4 acc[4][4];
#pragma unroll
  for (int i = 0; i < 4; i++)
#pragma unroll
    for (int j = 0; j < 4; j++) acc[i][j] = (f32x4){0.f, 0.f, 0.f, 0.f};

  uint4 ra0 = *(const uint4*)pa0;
  uint4 ra1 = *(const uint4*)pa1;
  uint4 rb0 = *(const uint4*)pb0;
  uint4 rb1 = *(const uint4*)pb1;

  for (int it = 0; it < iters; ++it) {
    *(uint4*)&As[row * APITCH + off] = ra0;
    *(uint4*)&As[(row + 64) * APITCH + off] = ra1;
    *(uint4*)&Bs[row * APITCH + off] = rb0;
    *(uint4*)&Bs[(row + 64) * APITCH + off] = rb1;
    __syncthreads();
    if (it + 1 < iters) {
      int d = (it + 1) * 32;
      ra0 = *(const uint4*)(pa0 + d);
      ra1 = *(const uint4*)(pa1 + d);
      rb0 = *(const uint4*)(pb0 + d);
      rb1 = *(const uint4*)(pb1 + d);
    }
    short8 af[4], bfv[4];
#pragma unroll
    for (int f = 0; f < 4; f++)
      af[f] = *(const short8*)&As[(wm + f * 16 + fr) * APITCH + kq];
#pragma unroll
    for (int f = 0; f < 4; f++)
      bfv[f] = *(const short8*)&Bs[(wn + f * 16 + fr) * APITCH + kq];
#pragma unroll
    for (int fm = 0; fm < 4; fm++)
#pragma unroll
      for (int fn = 0; fn < 4; fn++)
        acc[fm][fn] = __builtin_amdgcn_mfma_f32_16x16x32_bf16(af[fm], bfv[fn],
                                                              acc[fm][fn], 0, 0, 0);
    __syncthreads();
  }

  float* Cp = Cpart + (size_t)blockIdx.z * M * N;
  const int colb = n0 + wn + fr;
  const int rowb = m0 + wm + (lane >> 4) * 4;
#pragma unroll
  for (int fm = 0; fm < 4; fm++)
#pragma unroll
    for (int fn = 0; fn < 4; fn++)
#pragma unroll
      for (int r = 0; r < 4; r++)
        Cp[(size_t)(rowb + fm * 16 + r) * N + (colb + fn * 16)] = acc[fm][fn][r];
}

// ---------------- split-K reduce + bias + relu -> bf16 ----------------
__global__ __launch_bounds__(256) void reduce_bias_relu(
    const float* __restrict__ parts, int nparts, const float* __restrict__ bias,
    unsigned short* __restrict__ outb) {
  int i = blockIdx.x * 256 + threadIdx.x;  // total 256*1024
  float s = 0.0f;
  for (int p = 0; p < nparts; ++p) s += parts[(size_t)p * 262144 + i];
  s = fmaxf(s + bias[i & 1023], 0.0f);
  outb[i] = f2bf(s);
}

// ---------------- decode ----------------
__global__ __launch_bounds__(128) void decode_kernel(
    const float* __restrict__ headp, const float* __restrict__ bc,
    const float* __restrict__ bl,
    float* __restrict__ roi, float* __restrict__ valid,
    float* __restrict__ pre_b, float* __restrict__ pre_s,
    float st0, float st1, float st2, float st3, int stage) {
  int n = blockIdx.x;
  int t = threadIdx.x;
  __shared__ float red[128];
  __shared__ int redi[128];
  __shared__ float sroi[4];
  __shared__ float boxes[NCLS][4];

  if (t < 4) sroi[t] = roi[n * 4 + t];
  float l = -INFINITY;
  if (t < 81) {
    float s = 0.f;
#pragma unroll
    for (int z = 0; z < 4; z++) s += headp[(size_t)z * 131072 + n * 512 + t];
    l = s + bc[t];
  }
  red[t] = l;
  __syncthreads();
#pragma unroll
  for (int s = 64; s > 0; s >>= 1) {
    if (t < s) red[t] = fmaxf(red[t], red[t + s]);
    __syncthreads();
  }
  float mx = red[0];
  __syncthreads();
  red[t] = (t < 81) ? expf(l - mx) : 0.0f;
  __syncthreads();
#pragma unroll
  for (int s = 64; s > 0; s >>= 1) {
    if (t < s) red[t] += red[t + s];
    __syncthreads();
  }
  float denom = red[0];
  __syncthreads();

  float score = -INFINITY;
  if (t < NCLS) {
    float lj = 0.f;
#pragma unroll
    for (int z = 0; z < 4; z++) lj += headp[(size_t)z * 131072 + n * 512 + (t + 1)];
    lj += bc[t + 1];
    score = expf(lj - mx) / denom;
    float lp[4];
#pragma unroll
    for (int j = 0; j < 4; j++) {
      float s = 0.f;
#pragma unroll
      for (int z = 0; z < 4; z++)
        s += headp[(size_t)z * 131072 + n * 512 + 81 + (t + 1) * 4 + j];
      lp[j] = s + bl[(t + 1) * 4 + j];
    }
    float dy = lp[0] * st0;
    float dx = lp[1] * st1;
    float dh = lp[2] * st2;
    float dw = lp[3] * st3;
    float h_ = sroi[2] - sroi[0];
    float w_ = sroi[3] - sroi[1];
    float cy = sroi[0] + h_ * 0.5f;
    float cx = sroi[1] + w_ * 0.5f;
    float ny = dy * h_ + cy;
    float nx = dx * w_ + cx;
    float nh = expf(dh) * h_;
    float nw = expf(dw) * w_;
    float b0 = ny - nh * 0.5f;
    float b1v = nx - nw * 0.5f;
    float b2v = ny + nh * 0.5f;
    float b3v = nx + nw * 0.5f;
    int o = (n * NCLS + t) * 4;
    pre_b[o + 0] += b0;
    pre_b[o + 1] += b1v;
    pre_b[o + 2] += b2v;
    pre_b[o + 3] += b3v;
    pre_s[n * NCLS + t] += score;
    boxes[t][0] = b0;
    boxes[t][1] = b1v;
    boxes[t][2] = b2v;
    boxes[t][3] = b3v;
  }
  red[t] = score;
  redi[t] = t;
  __syncthreads();
  for (int s = 64; s > 0; s >>= 1) {
    if (t < s) {
      float o2 = red[t + s];
      int oi = redi[t + s];
      if (o2 > red[t] || (o2 == red[t] && oi < redi[t])) {
        red[t] = o2;
        redi[t] = oi;
      }
    }
    __syncthreads();
  }
  if (t == 0) {
    int best = redi[0];
    float ry1 = fminf(fmaxf(boxes[best][0], 0.0f), 1024.0f);
    float rx1 = fminf(fmaxf(boxes[best][1], 0.0f), 1024.0f);
    float ry2 = fminf(fmaxf(boxes[best][2], 0.0f), 1024.0f);
    float rx2 = fminf(fmaxf(boxes[best][3], 0.0f), 1024.0f);
    roi[n * 4 + 0] = ry1;
    roi[n * 4 + 1] = rx1;
    roi[n * 4 + 2] = ry2;
    roi[n * 4 + 3] = rx2;
    if (stage < 2) {
      float hh = ry2 - ry1, ww = rx2 - rx1;
      if (!(hh >= 16.0f && ww >= 16.0f)) valid[n] = 0.0f;
    }
  }
}

// ---------------- finalize ----------------
__global__ __launch_bounds__(256) void finalize_kernel(
    const float* __restrict__ pre_b, const float* __restrict__ pre_s,
    const float* __restrict__ valid, float* __restrict__ out) {
  int i = blockIdx.x * 256 + threadIdx.x;
  if (i < NROI * NCLS * 4) {
    int n = i / (NCLS * 4);
    out[i] = pre_b[i] * valid[n] * (1.0f / 3.0f);
  } else if (i < NROI * NCLS * 4 + NROI * NCLS) {
    int j = i - NROI * NCLS * 4;
    int n = j / NCLS;
    out[i] = pre_s[j] * valid[n] * (1.0f / 3.0f);
  }
}

extern "C" void kernel_launch(void* const* d_in, const int* in_sizes, int n_in,
                              void* d_out, int out_size, void* d_ws, size_t ws_size,
                              hipStream_t stream) {
  const float* P0 = (const float*)d_in[0];
  const float* P1 = (const float*)d_in[1];
  const float* P2 = (const float*)d_in[2];
  const float* P3 = (const float*)d_in[3];
  const float* rois = (const float*)d_in[4];
  float* out = (float*)d_out;
  float* ws = (float*)d_ws;

  // ---- ws layout (fp32 region, then bf16 region) ----
  float* roi   = ws;                      // 1024
  float* valid = roi + 1024;              // 256
  float* pre_b = valid + 256;             // 81920
  float* pre_s = pre_b + 81920;           // 20480
  float* part1 = pre_s + 20480;           // 14 * 262144
  float* part2 = part1 + 14 * 262144;     // 8 * 262144
  float* parth = part2 + 8 * 262144;      // 4 * 131072
  unsigned short* pooledb = (unsigned short*)(parth + 4 * 131072);  // 256*12544
  unsigned short* Wt1s = pooledb + (size_t)256 * 12544;   // 3 * 1024*12544
  unsigned short* Wt2s = Wt1s + (size_t)3 * 1024 * 12544; // 3 * 1024*1024
  unsigned short* Wths = Wt2s + (size_t)3 * 1024 * 1024;  // 3 * 512*1024
  unsigned short* h1b = Wths + (size_t)3 * 512 * 1024;    // 256*1024
  unsigned short* h2b = h1b + (size_t)256 * 1024;         // 256*1024
  unsigned short* Pb0 = h2b + (size_t)256 * 1024;         // 65536*256
  unsigned short* Pb1 = Pb0 + (size_t)65536 * 256;        // 16384*256
  unsigned short* Pb2 = Pb1 + (size_t)16384 * 256;        // 4096*256
  unsigned short* Pb3 = Pb2 + (size_t)4096 * 256;         // 1024*256

  PrepArgs pa;
  for (int s = 0; s < 3; s++) {
    pa.W1[s] = (const float*)d_in[5 + s * 8 + 0];
    pa.W2[s] = (const float*)d_in[5 + s * 8 + 2];
    pa.Wc[s] = (const float*)d_in[5 + s * 8 + 4];
    pa.Wl[s] = (const float*)d_in[5 + s * 8 + 6];
    pa.Wt1[s] = Wt1s + (size_t)s * 1024 * 12544;
    pa.Wt2[s] = Wt2s + (size_t)s * 1024 * 1024;
    pa.Wth[s] = Wths + (size_t)s * 512 * 1024;
  }
  pa.P[0] = P0; pa.P[1] = P1; pa.P[2] = P2; pa.P[3] = P3;
  pa.Pb[0] = Pb0; pa.Pb[1] = Pb1; pa.Pb[2] = Pb2; pa.Pb[3] = Pb3;
  pa.rois = rois;
  pa.roi = roi;
  pa.valid = valid;
  pa.zero_base = pre_b;
  pa.zero_count = 81920 + 20480;

  prep_all<<<4101, 256, 0, stream>>>(pa);

  const float stds[3][4] = {
      {0.1f, 0.1f, 0.2f, 0.2f},
      {0.05f, 0.05f, 0.1f, 0.1f},
      {1.0f / 30.0f, 1.0f / 30.0f, 1.0f / 15.0f, 1.0f / 15.0f}};

  for (int s = 0; s < 3; s++) {
    const float* b1 = (const float*)d_in[5 + s * 8 + 1];
    const float* b2 = (const float*)d_in[5 + s * 8 + 3];
    const float* bc = (const float*)d_in[5 + s * 8 + 5];
    const float* bl = (const float*)d_in[5 + s * 8 + 7];

    pool_kernel2<<<dim3(13, 256), 256, 0, stream>>>(Pb0, Pb1, Pb2, Pb3, roi, pooledb);

    // FC1: (256x12544)@(12544x1024)^T -> part1[14], iters = 392/14 = 28
    gemm_bf16<<<dim3(8, 2, 14), 256, 0, stream>>>(
        pooledb, pa.Wt1[s], part1, 256, 1024, 12544, 28);
    reduce_bias_relu<<<1024, 256, 0, stream>>>(part1, 14, b1, h1b);

    // FC2: (256x1024)@(1024x1024)^T -> part2[8], iters = 4
    gemm_bf16<<<dim3(8, 2, 8), 256, 0, stream>>>(
        h1b, pa.Wt2[s], part2, 256, 1024, 1024, 4);
    reduce_bias_relu<<<1024, 256, 0, stream>>>(part2, 8, b2, h2b);

    // fused heads: (256x1024)@(1024x512)^T -> parth[4], iters = 8
    gemm_bf16<<<dim3(4, 2, 4), 256, 0, stream>>>(
        h2b, pa.Wth[s], parth, 256, 512, 1024, 8);

    decode_kernel<<<256, 128, 0, stream>>>(parth, bc, bl, roi, valid, pre_b, pre_s,
                                           stds[s][0], stds[s][1], stds[s][2], stds[s][3], s);
  }

  finalize_kernel<<<400, 256, 0, stream>>>(pre_b, pre_s, valid, out);
}